// Round 11
// baseline (542.489 us; speedup 1.0000x reference)
//
#include <hip/hip_runtime.h>
#include <hip/hip_bf16.h>
#include <stdint.h>

#define T_TOK 4096
#define H_DIM 1024
#define F_DIM 4096
#define NE 8
#define MG_BLKS 40   // ceil((2T + 8*255)/256): max 256-aligned m-chunks

typedef float    f32x4  __attribute__((ext_vector_type(4)));
typedef __bf16   bf16x8 __attribute__((ext_vector_type(8)));
typedef uint16_t u16x8  __attribute__((ext_vector_type(8)));

#define AS1 __attribute__((address_space(1)))
#define AS3 __attribute__((address_space(3)))

__device__ __forceinline__ uint16_t f2bf(float f) {
  return __builtin_bit_cast(uint16_t, __float2bfloat16(f));
}

__device__ __forceinline__ void gld16(const void* g, void* l) {
  __builtin_amdgcn_global_load_lds((const AS1 void*)g, (AS3 void*)l, 16, 0, 0);
}

// ---------------- fp32 -> bf16 bulk convert (pure BW)
__global__ __launch_bounds__(256) void cvt_k(const float* __restrict__ src,
                                             uint16_t* __restrict__ dst, int n8) {
  const int stride = gridDim.x * blockDim.x;
  for (int i = blockIdx.x * blockDim.x + threadIdx.x; i < n8; i += stride) {
    const float* s = src + (size_t)i * 8;
    f32x4 a = *(const f32x4*)s;
    f32x4 b = *(const f32x4*)(s + 4);
    u16x8 o;
#pragma unroll
    for (int j = 0; j < 4; ++j) { o[j] = f2bf(a[j]); o[j + 4] = f2bf(b[j]); }
    *(u16x8*)(dst + (size_t)i * 8) = o;
  }
}

// ---------------- router: logits (fp32, exact), top-2 gates, compaction, x->bf16
__global__ __launch_bounds__(256) void router_k(
    const float* __restrict__ x, const float* __restrict__ wr,
    float* __restrict__ logits, uint16_t* __restrict__ xb,
    int* __restrict__ pairTok, float* __restrict__ pairGate,
    int* __restrict__ tokSlot, int* __restrict__ cnt)
{
  const int lane = threadIdx.x & 63;
  const int wid  = threadIdx.x >> 6;
  const int t    = blockIdx.x * 4 + wid;

  const float* xp = x + (size_t)t * H_DIM + lane * 16;
  f32x4 xv[4];
#pragma unroll
  for (int i = 0; i < 4; ++i) xv[i] = *(const f32x4*)(xp + 4 * i);

  u16x8 o0, o1;
#pragma unroll
  for (int j = 0; j < 4; ++j) {
    o0[j] = f2bf(xv[0][j]); o0[j + 4] = f2bf(xv[1][j]);
    o1[j] = f2bf(xv[2][j]); o1[j + 4] = f2bf(xv[3][j]);
  }
  uint16_t* xbp = xb + (size_t)t * H_DIM + lane * 16;
  *(u16x8*)xbp       = o0;
  *(u16x8*)(xbp + 8) = o1;

  float s[NE];
#pragma unroll
  for (int e = 0; e < NE; ++e) {
    const float* wp = wr + e * H_DIM + lane * 16;
    float acc = 0.f;
#pragma unroll
    for (int i = 0; i < 4; ++i) {
      f32x4 wv = *(const f32x4*)(wp + 4 * i);
#pragma unroll
      for (int j = 0; j < 4; ++j) acc += xv[i][j] * wv[j];
    }
#pragma unroll
    for (int off = 32; off > 0; off >>= 1) acc += __shfl_xor(acc, off, 64);
    s[e] = acc;
  }

  if (lane == 0) {
#pragma unroll
    for (int e = 0; e < NE; ++e) logits[t * NE + e] = s[e];
    int e1 = 0;
#pragma unroll
    for (int e = 1; e < NE; ++e) if (s[e] > s[e1]) e1 = e;
    int e2 = (e1 == 0) ? 1 : 0;
#pragma unroll
    for (int e = 0; e < NE; ++e)
      if (e != e1 && e != e2 && s[e] > s[e2]) e2 = e;
    const float d  = s[e2] - s[e1];              // <= 0
    const float g1 = 1.f / (1.f + __expf(d));
    const float g2 = 1.f - g1;
    int i1 = atomicAdd(cnt + e1, 1);
    pairTok[e1 * T_TOK + i1] = t;  pairGate[e1 * T_TOK + i1] = g1;
    int i2 = atomicAdd(cnt + e2, 1);
    pairTok[e2 * T_TOK + i2] = t;  pairGate[e2 * T_TOK + i2] = g2;
    int4 sl; sl.x = e1; sl.y = i1; sl.z = e2; sl.w = i2;
    ((int4*)tokSlot)[t] = sl;
  }
}

// ---------------- prefix: 256-aligned bases; base[NE] = padded total
__global__ void prefix_k(const int* __restrict__ cnt, int* __restrict__ base) {
  if (threadIdx.x == 0) {
    int b = 0;
#pragma unroll
    for (int e = 0; e < NE; ++e) { base[e] = b; b += (cnt[e] + 255) & ~255; }
    base[NE] = b;
  }
}

// ================= bf16-weight path =================

// stage 1 (PIPELINED): h = gate * silu(x@w1^T) * (x@w3^T)
// BM=256 x BN=128, BK=64, 512 thr = 8 waves (2M x 4N), wave tile 128x32.
// Double-buffered LDS (128 KB exactly), counted vmcnt(8) — tile t+1's loads
// stay in flight across barriers; no vmcnt(0) drain in the main loop (T3/T4).
__global__ __launch_bounds__(512, 1) void ffn1b_k(
    const uint16_t* __restrict__ xb, const uint16_t* __restrict__ w1b,
    const uint16_t* __restrict__ w3b, uint16_t* __restrict__ hbuf,
    const int* __restrict__ pairTok, const float* __restrict__ pairGate,
    const int* __restrict__ cnt, const int* __restrict__ base)
{
  const int mg0 = blockIdx.y * 256;
  if (mg0 >= base[NE]) return;
  int e = 0;
#pragma unroll
  for (int k = 1; k < NE; ++k) if (mg0 >= base[k]) e = k;
  const int m0   = mg0 - base[e];
  const int cnte = cnt[e];
  const int n0   = blockIdx.x * 128;
  const int tid  = threadIdx.x;
  const int lane = tid & 63;
  const int wid  = tid >> 6;           // 0..7
  const int wm   = (wid >> 2) * 128;   // 0 or 128
  const int wn   = (wid & 3) * 32;     // 0,32,64,96

  // 128 KB total: A dbuf 64K + B1 dbuf 32K + B3 dbuf 32K
  __shared__ __align__(16) uint16_t lsA [2][256 * 64];
  __shared__ __align__(16) uint16_t lsB1[2][128 * 64];
  __shared__ __align__(16) uint16_t lsB3[2][128 * 64];

  const uint16_t* w1e = w1b + (size_t)e * F_DIM * H_DIM;
  const uint16_t* w3e = w3b + (size_t)e * F_DIM * H_DIM;

  // A: 2048 chunks, 4/thread; B1/B3: 1024 chunks, 2/thread each. 8 gld16/thread/tile.
  const uint16_t* asrc[4];
#pragma unroll
  for (int q = 0; q < 4; ++q) {
    const int c = q * 512 + tid;
    const int row = c >> 3, pos = c & 7;
    const int kc  = pos ^ (row & 7);
    int ar = m0 + row; if (ar >= cnte) ar = cnte - 1;
    const int tok = pairTok[e * T_TOK + ar];
    asrc[q] = xb + (size_t)tok * H_DIM + kc * 8;
  }
  const uint16_t* b1src[2];
  const uint16_t* b3src[2];
#pragma unroll
  for (int q = 0; q < 2; ++q) {
    const int c = q * 512 + tid;
    const int row = c >> 3, pos = c & 7;
    const int kc  = pos ^ (row & 7);
    b1src[q] = w1e + (size_t)(n0 + row) * H_DIM + kc * 8;
    b3src[q] = w3e + (size_t)(n0 + row) * H_DIM + kc * 8;
  }

#define STAGE1(buf, koff)                                                 \
  {                                                                       \
    _Pragma("unroll") for (int q = 0; q < 4; ++q)                         \
      gld16(asrc[q] + (koff), &lsA[buf][(q * 512 + tid) * 8]);            \
    _Pragma("unroll") for (int q = 0; q < 2; ++q) {                       \
      gld16(b1src[q] + (koff), &lsB1[buf][(q * 512 + tid) * 8]);          \
      gld16(b3src[q] + (koff), &lsB3[buf][(q * 512 + tid) * 8]);          \
    }                                                                     \
  }

#define COMPUTE1(cur)                                                     \
  {                                                                       \
    _Pragma("unroll") for (int ks = 0; ks < 2; ++ks) {                    \
      const int kg = ks * 4 + (lane >> 4);                                \
      bf16x8 af[8], b1f[2], b3f[2];                                       \
      _Pragma("unroll") for (int i = 0; i < 8; ++i) {                     \
        const int ar = wm + i * 16 + (lane & 15);                         \
        af[i] = *(const bf16x8*)&lsA[cur][ar * 64 + ((kg ^ (ar & 7)) * 8)]; \
      }                                                                   \
      _Pragma("unroll") for (int j = 0; j < 2; ++j) {                     \
        const int br = wn + j * 16 + (lane & 15);                         \
        b1f[j] = *(const bf16x8*)&lsB1[cur][br * 64 + ((kg ^ (br & 7)) * 8)]; \
        b3f[j] = *(const bf16x8*)&lsB3[cur][br * 64 + ((kg ^ (br & 7)) * 8)]; \
      }                                                                   \
      _Pragma("unroll") for (int i = 0; i < 8; ++i)                       \
        _Pragma("unroll") for (int j = 0; j < 2; ++j) {                   \
          acc1[i][j] = __builtin_amdgcn_mfma_f32_16x16x32_bf16(af[i], b1f[j], acc1[i][j], 0, 0, 0); \
          acc3[i][j] = __builtin_amdgcn_mfma_f32_16x16x32_bf16(af[i], b3f[j], acc3[i][j], 0, 0, 0); \
        }                                                                 \
    }                                                                     \
  }

  const f32x4 fz = {0.f, 0.f, 0.f, 0.f};
  f32x4 acc1[8][2], acc3[8][2];
#pragma unroll
  for (int i = 0; i < 8; ++i)
#pragma unroll
    for (int j = 0; j < 2; ++j) { acc1[i][j] = fz; acc3[i][j] = fz; }

  const int NT = H_DIM / 64;   // 16
  // prologue: tiles 0 and 1 in flight (8 loads each per wave)
  STAGE1(0, 0)
  STAGE1(1, 64)

  for (int t = 0; t < NT - 1; ++t) {
    const int cur = t & 1;
    asm volatile("s_waitcnt vmcnt(8)" ::: "memory");  // tile t landed; t+1 in flight
    __builtin_amdgcn_s_barrier();                     // all waves see tile t
    COMPUTE1(cur)
    __builtin_amdgcn_s_barrier();                     // all waves done reading buf[cur]
    if (t + 2 < NT) STAGE1(cur, (t + 2) * 64)         // refill the buffer just freed
  }
  {
    asm volatile("s_waitcnt vmcnt(0)" ::: "memory");  // final tile
    __builtin_amdgcn_s_barrier();
    COMPUTE1((NT - 1) & 1)
  }
#undef STAGE1
#undef COMPUTE1

  // epilogue: h = g * silu(a1) * a3 -> bf16. C/D: col=lane&15, row=(lane>>4)*4+r
  const int be = base[e];
#pragma unroll
  for (int i = 0; i < 8; ++i) {
#pragma unroll
    for (int r = 0; r < 4; ++r) {
      const int lrow = m0 + wm + i * 16 + (lane >> 4) * 4 + r;
      if (lrow < cnte) {
        const float g = pairGate[e * T_TOK + lrow];
        uint16_t* hp = hbuf + (size_t)(be + lrow) * F_DIM + n0 + wn + (lane & 15);
#pragma unroll
        for (int j = 0; j < 2; ++j) {
          const float a  = acc1[i][j][r];
          const float hv = g * (a / (1.f + __expf(-a))) * acc3[i][j][r];
          hp[j * 16] = f2bf(hv);
        }
      }
    }
  }
}

// stage 2: y[row] = h[row] @ w2^T; BM=256 x BN=128, 4 waves, pure gld16 (R10-proven).
__global__ __launch_bounds__(256, 2) void ffn2b_k(
    const uint16_t* __restrict__ hbuf, const uint16_t* __restrict__ w2b,
    uint16_t* __restrict__ y, const int* __restrict__ cnt,
    const int* __restrict__ base)
{
  const int mg0 = blockIdx.y * 256;
  if (mg0 >= base[NE]) return;
  int e = 0;
#pragma unroll
  for (int k = 1; k < NE; ++k) if (mg0 >= base[k]) e = k;
  const int m0   = mg0 - base[e];
  const int cnte = cnt[e];
  const int n0   = blockIdx.x * 128;
  const int tid  = threadIdx.x;
  const int lane = tid & 63;
  const int wid  = tid >> 6;
  const int wm   = (wid >> 1) * 128;
  const int wn   = (wid & 1) * 64;

  __shared__ __align__(16) uint16_t lsA[256 * 64];   // 32 KB
  __shared__ __align__(16) uint16_t lsB[128 * 64];   // 16 KB

  const int be = base[e];
  const uint16_t* w2e = w2b + (size_t)e * H_DIM * F_DIM;

  const uint16_t* asrc[8];
#pragma unroll
  for (int q = 0; q < 8; ++q) {
    const int c = q * 256 + tid;
    const int row = c >> 3, pos = c & 7;
    const int kc  = pos ^ (row & 7);
    int rr = m0 + row; if (rr >= cnte) rr = cnte - 1;
    asrc[q] = hbuf + (size_t)(be + rr) * F_DIM + kc * 8;
  }
  const uint16_t* bsrc[4];
#pragma unroll
  for (int q = 0; q < 4; ++q) {
    const int c = q * 256 + tid;
    const int row = c >> 3, pos = c & 7;
    const int kc  = pos ^ (row & 7);
    bsrc[q] = w2e + (size_t)(n0 + row) * F_DIM + kc * 8;
  }

  const f32x4 fz = {0.f, 0.f, 0.f, 0.f};
  f32x4 acc[8][4];
#pragma unroll
  for (int i = 0; i < 8; ++i)
#pragma unroll
    for (int j = 0; j < 4; ++j) acc[i][j] = fz;

  for (int kt = 0; kt < F_DIM; kt += 64) {
    __syncthreads();
#pragma unroll
    for (int q = 0; q < 8; ++q)
      gld16(asrc[q] + kt, &lsA[(q * 256 + tid) * 8]);
#pragma unroll
    for (int q = 0; q < 4; ++q)
      gld16(bsrc[q] + kt, &lsB[(q * 256 + tid) * 8]);
    __syncthreads();
#pragma unroll
    for (int ks = 0; ks < 2; ++ks) {
      const int kg = ks * 4 + (lane >> 4);
      bf16x8 af[8], bf[4];
#pragma unroll
      for (int i = 0; i < 8; ++i) {
        const int ar = wm + i * 16 + (lane & 15);
        af[i] = *(const bf16x8*)&lsA[ar * 64 + ((kg ^ (ar & 7)) * 8)];
      }
#pragma unroll
      for (int j = 0; j < 4; ++j) {
        const int br = wn + j * 16 + (lane & 15);
        bf[j] = *(const bf16x8*)&lsB[br * 64 + ((kg ^ (br & 7)) * 8)];
      }
#pragma unroll
      for (int i = 0; i < 8; ++i)
#pragma unroll
        for (int j = 0; j < 4; ++j)
          acc[i][j] = __builtin_amdgcn_mfma_f32_16x16x32_bf16(af[i], bf[j], acc[i][j], 0, 0, 0);
    }
  }

#pragma unroll
  for (int i = 0; i < 8; ++i) {
#pragma unroll
    for (int r = 0; r < 4; ++r) {
      const int lrow = m0 + wm + i * 16 + (lane >> 4) * 4 + r;
      if (lrow < cnte) {
        uint16_t* yp = y + (size_t)(be + lrow) * H_DIM + n0 + wn + (lane & 15);
#pragma unroll
        for (int j = 0; j < 4; ++j)
          yp[j * 16] = f2bf(acc[i][j][r]);
      }
    }
  }
}

// ================= fp32-weight fallback path (R9-verified) =================

__global__ __launch_bounds__(256, 2) void ffn1_k(
    const uint16_t* __restrict__ xb, const float* __restrict__ w1,
    const float* __restrict__ w3, uint16_t* __restrict__ hbuf,
    const int* __restrict__ pairTok, const float* __restrict__ pairGate,
    const int* __restrict__ cnt, const int* __restrict__ base)
{
  const int mg0 = blockIdx.y * 256;
  if (mg0 >= base[NE]) return;
  int e = 0;
#pragma unroll
  for (int k = 1; k < NE; ++k) if (mg0 >= base[k]) e = k;
  const int m0   = mg0 - base[e];
  const int cnte = cnt[e];
  const int n0   = blockIdx.x * 64;
  const int tid  = threadIdx.x;
  const int lane = tid & 63;
  const int wid  = tid >> 6;
  const int wm   = (wid >> 1) * 128;
  const int wn   = (wid & 1) * 32;

  __shared__ __align__(16) uint16_t lsA [256 * 64];
  __shared__ __align__(16) uint16_t lsB1[ 64 * 64];
  __shared__ __align__(16) uint16_t lsB3[ 64 * 64];
  __shared__ float lsG[256];

  {
    const int rr = m0 + tid;
    lsG[tid] = (rr < cnte) ? pairGate[e * T_TOK + rr] : 0.f;
  }

  const float* w1e = w1 + (size_t)e * F_DIM * H_DIM;
  const float* w3e = w3 + (size_t)e * F_DIM * H_DIM;

  const uint16_t* asrc[8];
#pragma unroll
  for (int q = 0; q < 8; ++q) {
    const int c = q * 256 + tid;
    const int row = c >> 3, pos = c & 7;
    const int kc  = pos ^ (row & 7);
    int ar = m0 + row; if (ar >= cnte) ar = cnte - 1;
    const int tok = pairTok[e * T_TOK + ar];
    asrc[q] = xb + (size_t)tok * H_DIM + kc * 8;
  }
  const float* b1src[2];
  const float* b3src[2];
  int bdst[2];
#pragma unroll
  for (int q = 0; q < 2; ++q) {
    const int c = q * 256 + tid;
    const int row = c >> 3, pos = c & 7;
    const int kc  = pos ^ (row & 7);
    bdst[q] = c * 8;
    b1src[q] = w1e + (size_t)(n0 + row) * H_DIM + kc * 8;
    b3src[q] = w3e + (size_t)(n0 + row) * H_DIM + kc * 8;
  }

  const f32x4 fz = {0.f, 0.f, 0.f, 0.f};
  f32x4 acc1[8][2], acc3[8][2];
#pragma unroll
  for (int i = 0; i < 8; ++i)
#pragma unroll
    for (int j = 0; j < 2; ++j) { acc1[i][j] = fz; acc3[i][j] = fz; }

  for (int kt = 0; kt < H_DIM; kt += 64) {
    __syncthreads();
#pragma unroll
    for (int q = 0; q < 8; ++q)
      gld16(asrc[q] + kt, &lsA[(q * 256 + tid) * 8]);
#pragma unroll
    for (int q = 0; q < 2; ++q) {
      const float* s1 = b1src[q] + kt;
      const float* s3 = b3src[q] + kt;
      f32x4 a0 = *(const f32x4*)s1;
      f32x4 a1 = *(const f32x4*)(s1 + 4);
      f32x4 c0 = *(const f32x4*)s3;
      f32x4 c1 = *(const f32x4*)(s3 + 4);
      u16x8 ob1, ob3;
#pragma unroll
      for (int j = 0; j < 4; ++j) {
        ob1[j] = f2bf(a0[j]); ob1[j + 4] = f2bf(a1[j]);
        ob3[j] = f2bf(c0[j]); ob3[j + 4] = f2bf(c1[j]);
      }
      *(u16x8*)&lsB1[bdst[q]] = ob1;
      *(u16x8*)&lsB3[bdst[q]] = ob3;
    }
    __syncthreads();
#pragma unroll
    for (int ks = 0; ks < 2; ++ks) {
      const int kg = ks * 4 + (lane >> 4);
      bf16x8 af[8], b1f[2], b3f[2];
#pragma unroll
      for (int i = 0; i < 8; ++i) {
        const int ar = wm + i * 16 + (lane & 15);
        af[i] = *(const bf16x8*)&lsA[ar * 64 + ((kg ^ (ar & 7)) * 8)];
      }
#pragma unroll
      for (int j = 0; j < 2; ++j) {
        const int br = wn + j * 16 + (lane & 15);
        b1f[j] = *(const bf16x8*)&lsB1[br * 64 + ((kg ^ (br & 7)) * 8)];
        b3f[j] = *(const bf16x8*)&lsB3[br * 64 + ((kg ^ (br & 7)) * 8)];
      }
#pragma unroll
      for (int i = 0; i < 8; ++i)
#pragma unroll
        for (int j = 0; j < 2; ++j) {
          acc1[i][j] = __builtin_amdgcn_mfma_f32_16x16x32_bf16(af[i], b1f[j], acc1[i][j], 0, 0, 0);
          acc3[i][j] = __builtin_amdgcn_mfma_f32_16x16x32_bf16(af[i], b3f[j], acc3[i][j], 0, 0, 0);
        }
    }
  }

  const int be = base[e];
#pragma unroll
  for (int i = 0; i < 8; ++i) {
#pragma unroll
    for (int r = 0; r < 4; ++r) {
      const int lrow = m0 + wm + i * 16 + (lane >> 4) * 4 + r;
      if (lrow < cnte) {
        const float g = lsG[lrow - m0];
        uint16_t* hp = hbuf + (size_t)(be + lrow) * F_DIM + n0 + wn + (lane & 15);
#pragma unroll
        for (int j = 0; j < 2; ++j) {
          const float a  = acc1[i][j][r];
          const float hv = g * (a / (1.f + __expf(-a))) * acc3[i][j][r];
          hp[j * 16] = f2bf(hv);
        }
      }
    }
  }
}

__global__ __launch_bounds__(256, 2) void ffn2_k(
    const uint16_t* __restrict__ hbuf, const float* __restrict__ w2,
    uint16_t* __restrict__ y, const int* __restrict__ cnt,
    const int* __restrict__ base)
{
  const int mg0 = blockIdx.y * 256;
  if (mg0 >= base[NE]) return;
  int e = 0;
#pragma unroll
  for (int k = 1; k < NE; ++k) if (mg0 >= base[k]) e = k;
  const int m0   = mg0 - base[e];
  const int cnte = cnt[e];
  const int n0   = blockIdx.x * 128;
  const int tid  = threadIdx.x;
  const int lane = tid & 63;
  const int wid  = tid >> 6;
  const int wm   = (wid >> 1) * 128;
  const int wn   = (wid & 1) * 64;

  __shared__ __align__(16) uint16_t lsA[256 * 64];
  __shared__ __align__(16) uint16_t lsB[128 * 64];

  const int be = base[e];
  const float* w2e = w2 + (size_t)e * H_DIM * F_DIM;

  const uint16_t* asrc[8];
#pragma unroll
  for (int q = 0; q < 8; ++q) {
    const int c = q * 256 + tid;
    const int row = c >> 3, pos = c & 7;
    const int kc  = pos ^ (row & 7);
    int rr = m0 + row; if (rr >= cnte) rr = cnte - 1;
    asrc[q] = hbuf + (size_t)(be + rr) * F_DIM + kc * 8;
  }
  const float* bsrc[4];
  int bdst[4];
#pragma unroll
  for (int q = 0; q < 4; ++q) {
    const int c = q * 256 + tid;
    const int row = c >> 3, pos = c & 7;
    const int kc  = pos ^ (row & 7);
    bdst[q] = c * 8;
    bsrc[q] = w2e + (size_t)(n0 + row) * F_DIM + kc * 8;
  }

  const f32x4 fz = {0.f, 0.f, 0.f, 0.f};
  f32x4 acc[8][4];
#pragma unroll
  for (int i = 0; i < 8; ++i)
#pragma unroll
    for (int j = 0; j < 4; ++j) acc[i][j] = fz;

  for (int kt = 0; kt < F_DIM; kt += 64) {
    __syncthreads();
#pragma unroll
    for (int q = 0; q < 8; ++q)
      gld16(asrc[q] + kt, &lsA[(q * 256 + tid) * 8]);
#pragma unroll
    for (int q = 0; q < 4; ++q) {
      const float* sb = bsrc[q] + kt;
      f32x4 b0 = *(const f32x4*)sb;
      f32x4 b1 = *(const f32x4*)(sb + 4);
      u16x8 ob;
#pragma unroll
      for (int j = 0; j < 4; ++j) { ob[j] = f2bf(b0[j]); ob[j + 4] = f2bf(b1[j]); }
      *(u16x8*)&lsB[bdst[q]] = ob;
    }
    __syncthreads();
#pragma unroll
    for (int ks = 0; ks < 2; ++ks) {
      const int kg = ks * 4 + (lane >> 4);
      bf16x8 af[8], bf[4];
#pragma unroll
      for (int i = 0; i < 8; ++i) {
        const int ar = wm + i * 16 + (lane & 15);
        af[i] = *(const bf16x8*)&lsA[ar * 64 + ((kg ^ (ar & 7)) * 8)];
      }
#pragma unroll
      for (int j = 0; j < 4; ++j) {
        const int br = wn + j * 16 + (lane & 15);
        bf[j] = *(const bf16x8*)&lsB[br * 64 + ((kg ^ (br & 7)) * 8)];
      }
#pragma unroll
      for (int i = 0; i < 8; ++i)
#pragma unroll
        for (int j = 0; j < 4; ++j)
          acc[i][j] = __builtin_amdgcn_mfma_f32_16x16x32_bf16(af[i], bf[j], acc[i][j], 0, 0, 0);
    }
  }

#pragma unroll
  for (int i = 0; i < 8; ++i) {
#pragma unroll
    for (int r = 0; r < 4; ++r) {
      const int lrow = m0 + wm + i * 16 + (lane >> 4) * 4 + r;
      if (lrow < cnte) {
        uint16_t* yp = y + (size_t)(be + lrow) * H_DIM + n0 + wn + (lane & 15);
#pragma unroll
        for (int j = 0; j < 4; ++j)
          yp[j * 16] = f2bf(acc[i][j][r]);
      }
    }
  }
}

// ---------------- combine: out[t] = y[slot1(t)] + y[slot2(t)]  (fp32 out)
__global__ __launch_bounds__(256) void combine_k(
    const uint16_t* __restrict__ y, const int* __restrict__ tokSlot,
    const int* __restrict__ base, float* __restrict__ out)
{
  const int t = blockIdx.x * 2 + (threadIdx.x >> 7);
  const int c = (threadIdx.x & 127) * 8;
  const int4 s = ((const int4*)tokSlot)[t];
  const uint16_t* y1 = y + (size_t)(base[s.x] + s.y) * H_DIM + c;
  const uint16_t* y2 = y + (size_t)(base[s.z] + s.w) * H_DIM + c;
  const u16x8 a = *(const u16x8*)y1;
  const u16x8 b = *(const u16x8*)y2;
  float* op = out + (size_t)t * H_DIM + c;
  f32x4 o0, o1;
#pragma unroll
  for (int j = 0; j < 4; ++j) {
    o0[j] = __bfloat162float(__hip_bfloat16_raw{a[j]}) +
            __bfloat162float(__hip_bfloat16_raw{b[j]});
    o1[j] = __bfloat162float(__hip_bfloat16_raw{a[j + 4]}) +
            __bfloat162float(__hip_bfloat16_raw{b[j + 4]});
  }
  *(f32x4*)op       = o0;
  *(f32x4*)(op + 4) = o1;
}

extern "C" void kernel_launch(void* const* d_in, const int* in_sizes, int n_in,
                              void* d_out, int out_size, void* d_ws, size_t ws_size,
                              hipStream_t stream)
{
  const float* x  = (const float*)d_in[0];
  const float* wr = (const float*)d_in[1];
  const float* w1 = (const float*)d_in[2];
  const float* w2 = (const float*)d_in[3];
  const float* w3 = (const float*)d_in[4];
  float* out    = (float*)d_out;
  float* logits = out + (size_t)T_TOK * H_DIM;

  uint8_t* ws = (uint8_t*)d_ws;
  const size_t PADROWS  = (size_t)MG_BLKS * 256;                    // 10240
  const size_t WELEMS   = (size_t)NE * F_DIM * H_DIM;               // 33.55M
  const size_t XB_OFF   = 0;
  const size_t HB_OFF   = XB_OFF + (size_t)T_TOK * H_DIM * 2;       // 8 MB
  const size_t Y_OFF    = HB_OFF + PADROWS * F_DIM * 2;             // +80 MB
  const size_t PT_OFF   = Y_OFF + PADROWS * H_DIM * 2;              // +20 MB
  const size_t PG_OFF   = PT_OFF + (size_t)NE * T_TOK * 4;
  const size_t TS_OFF   = PG_OFF + (size_t)NE * T_TOK * 4;
  const size_t CNT_OFF  = TS_OFF + (size_t)T_TOK * 16;
  const size_t BASE_OFF = CNT_OFF + 64;
  const size_t W1B_OFF  = (BASE_OFF + 64 + 255) & ~(size_t)255;
  const size_t W3B_OFF  = W1B_OFF + WELEMS * 2;                     // 67.1 MB each
  const size_t W2B_OFF  = W3B_OFF + WELEMS * 2;
  const size_t NEED_BIG = W2B_OFF + WELEMS * 2;
  const size_t NEED_SM  = W1B_OFF;
  if (ws_size < NEED_SM) return;

  uint16_t* xb      = (uint16_t*)(ws + XB_OFF);
  uint16_t* hb      = (uint16_t*)(ws + HB_OFF);
  uint16_t* yb      = (uint16_t*)(ws + Y_OFF);
  int*      pairTok = (int*)(ws + PT_OFF);
  float*    pairGate= (float*)(ws + PG_OFF);
  int*      tokSlot = (int*)(ws + TS_OFF);
  int*      cnt     = (int*)(ws + CNT_OFF);
  int*      basep   = (int*)(ws + BASE_OFF);

  hipMemsetAsync(cnt, 0, 64, stream);
  router_k<<<T_TOK / 4, 256, 0, stream>>>(x, wr, logits, xb, pairTok, pairGate, tokSlot, cnt);
  prefix_k<<<1, 64, 0, stream>>>(cnt, basep);

  if (ws_size >= NEED_BIG) {
    uint16_t* w1b = (uint16_t*)(ws + W1B_OFF);
    uint16_t* w3b = (uint16_t*)(ws + W3B_OFF);
    uint16_t* w2b = (uint16_t*)(ws + W2B_OFF);
    const int n8 = (int)(WELEMS / 8);
    cvt_k<<<2048, 256, 0, stream>>>(w1, w1b, n8);
    cvt_k<<<2048, 256, 0, stream>>>(w3, w3b, n8);
    cvt_k<<<2048, 256, 0, stream>>>(w2, w2b, n8);
    ffn1b_k<<<dim3(F_DIM / 128, MG_BLKS, 1), 512, 0, stream>>>(xb, w1b, w3b, hb, pairTok, pairGate, cnt, basep);
    ffn2b_k<<<dim3(H_DIM / 128, MG_BLKS, 1), 256, 0, stream>>>(hb, w2b, yb, cnt, basep);
  } else {
    ffn1_k<<<dim3(F_DIM / 64, MG_BLKS, 1), 256, 0, stream>>>(xb, w1, w3, hb, pairTok, pairGate, cnt, basep);
    ffn2_k<<<dim3(H_DIM / 128, MG_BLKS, 1), 256, 0, stream>>>(hb, w2, yb, cnt, basep);
  }
  combine_k<<<T_TOK / 2, 256, 0, stream>>>(yb, tokSlot, basep, out);
}

// Round 12
// 469.906 us; speedup vs baseline: 1.1545x; 1.1545x over previous
//
#include <hip/hip_runtime.h>
#include <hip/hip_bf16.h>
#include <stdint.h>

#define T_TOK 4096
#define H_DIM 1024
#define F_DIM 4096
#define NE 8
#define MG_BLKS 40   // ceil((2T + 8*255)/256): max 256-aligned m-chunks

typedef float    f32x4  __attribute__((ext_vector_type(4)));
typedef __bf16   bf16x8 __attribute__((ext_vector_type(8)));
typedef uint16_t u16x8  __attribute__((ext_vector_type(8)));

#define AS1 __attribute__((address_space(1)))
#define AS3 __attribute__((address_space(3)))

__device__ __forceinline__ uint16_t f2bf(float f) {
  return __builtin_bit_cast(uint16_t, __float2bfloat16(f));
}

__device__ __forceinline__ void gld16(const void* g, void* l) {
  __builtin_amdgcn_global_load_lds((const AS1 void*)g, (AS3 void*)l, 16, 0, 0);
}

#define FENCE() asm volatile("" ::: "memory")

// ---------------- router: logits (fp32, exact), top-2 gates, compaction, x->bf16
__global__ __launch_bounds__(256) void router_k(
    const float* __restrict__ x, const float* __restrict__ wr,
    float* __restrict__ logits, uint16_t* __restrict__ xb,
    int* __restrict__ pairTok, float* __restrict__ pairGate,
    int* __restrict__ tokSlot, int* __restrict__ cnt)
{
  const int lane = threadIdx.x & 63;
  const int wid  = threadIdx.x >> 6;
  const int t    = blockIdx.x * 4 + wid;

  const float* xp = x + (size_t)t * H_DIM + lane * 16;
  f32x4 xv[4];
#pragma unroll
  for (int i = 0; i < 4; ++i) xv[i] = *(const f32x4*)(xp + 4 * i);

  u16x8 o0, o1;
#pragma unroll
  for (int j = 0; j < 4; ++j) {
    o0[j] = f2bf(xv[0][j]); o0[j + 4] = f2bf(xv[1][j]);
    o1[j] = f2bf(xv[2][j]); o1[j + 4] = f2bf(xv[3][j]);
  }
  uint16_t* xbp = xb + (size_t)t * H_DIM + lane * 16;
  *(u16x8*)xbp       = o0;
  *(u16x8*)(xbp + 8) = o1;

  float s[NE];
#pragma unroll
  for (int e = 0; e < NE; ++e) {
    const float* wp = wr + e * H_DIM + lane * 16;
    float acc = 0.f;
#pragma unroll
    for (int i = 0; i < 4; ++i) {
      f32x4 wv = *(const f32x4*)(wp + 4 * i);
#pragma unroll
      for (int j = 0; j < 4; ++j) acc += xv[i][j] * wv[j];
    }
#pragma unroll
    for (int off = 32; off > 0; off >>= 1) acc += __shfl_xor(acc, off, 64);
    s[e] = acc;
  }

  if (lane == 0) {
#pragma unroll
    for (int e = 0; e < NE; ++e) logits[t * NE + e] = s[e];
    int e1 = 0;
#pragma unroll
    for (int e = 1; e < NE; ++e) if (s[e] > s[e1]) e1 = e;
    int e2 = (e1 == 0) ? 1 : 0;
#pragma unroll
    for (int e = 0; e < NE; ++e)
      if (e != e1 && e != e2 && s[e] > s[e2]) e2 = e;
    const float d  = s[e2] - s[e1];              // <= 0
    const float g1 = 1.f / (1.f + __expf(d));
    const float g2 = 1.f - g1;
    int i1 = atomicAdd(cnt + e1, 1);
    pairTok[e1 * T_TOK + i1] = t;  pairGate[e1 * T_TOK + i1] = g1;
    int i2 = atomicAdd(cnt + e2, 1);
    pairTok[e2 * T_TOK + i2] = t;  pairGate[e2 * T_TOK + i2] = g2;
    int4 sl; sl.x = e1; sl.y = i1; sl.z = e2; sl.w = i2;
    ((int4*)tokSlot)[t] = sl;
  }
}

// ---------------- prefix: 256-aligned bases; base[NE] = padded total
__global__ void prefix_k(const int* __restrict__ cnt, int* __restrict__ base) {
  if (threadIdx.x == 0) {
    int b = 0;
#pragma unroll
    for (int e = 0; e < NE; ++e) { base[e] = b; b += (cnt[e] + 255) & ~255; }
    base[NE] = b;
  }
}

// ---------------- stage 1: h = gate * silu(x@w1^T) * (x@w3^T)
// R9 geometry (BM=256 x BN=64, BK=64, 256 thr, 4 waves, wave 128x32, dual acc).
// NEW: A double-buffered (issue t+2 right after compute barrier), B fp32 loaded
// one tile early into regs (T14), cvt+ds_write after the barrier. No vmcnt(0)
// drain before the pre-compute barrier — only lgkmcnt(0). setprio on MFMA.
// LDS = 2x32K (A) + 8K + 8K (B1,B3) = 80 KB -> 2 blocks/CU.
__global__ __launch_bounds__(256, 2) void ffn1_k(
    const uint16_t* __restrict__ xb, const float* __restrict__ w1,
    const float* __restrict__ w3, uint16_t* __restrict__ hbuf,
    const int* __restrict__ pairTok, const float* __restrict__ pairGate,
    const int* __restrict__ cnt, const int* __restrict__ base)
{
  const int mg0 = blockIdx.y * 256;
  if (mg0 >= base[NE]) return;
  int e = 0;
#pragma unroll
  for (int k = 1; k < NE; ++k) if (mg0 >= base[k]) e = k;
  const int m0   = mg0 - base[e];
  const int cnte = cnt[e];
  const int n0   = blockIdx.x * 64;
  const int tid  = threadIdx.x;
  const int lane = tid & 63;
  const int wid  = tid >> 6;
  const int wm   = (wid >> 1) * 128;   // 0 or 128
  const int wn   = (wid & 1) * 32;     // 0 or 32

  __shared__ __align__(16) uint16_t lsA [2][256 * 64];  // 64 KB
  __shared__ __align__(16) uint16_t lsB1[ 64 * 64];     //  8 KB
  __shared__ __align__(16) uint16_t lsB3[ 64 * 64];     //  8 KB

  const float* w1e = w1 + (size_t)e * F_DIM * H_DIM;
  const float* w3e = w3 + (size_t)e * F_DIM * H_DIM;

  const uint16_t* asrc[8];
#pragma unroll
  for (int q = 0; q < 8; ++q) {
    const int c = q * 256 + tid;
    const int row = c >> 3, pos = c & 7;
    const int kc  = pos ^ (row & 7);
    int ar = m0 + row; if (ar >= cnte) ar = cnte - 1;
    const int tok = pairTok[e * T_TOK + ar];
    asrc[q] = xb + (size_t)tok * H_DIM + kc * 8;
  }
  const float* b1src[2];
  const float* b3src[2];
  int bdst[2];
#pragma unroll
  for (int q = 0; q < 2; ++q) {
    const int c = q * 256 + tid;
    const int row = c >> 3, pos = c & 7;
    const int kc  = pos ^ (row & 7);
    bdst[q] = c * 8;
    b1src[q] = w1e + (size_t)(n0 + row) * H_DIM + kc * 8;
    b3src[q] = w3e + (size_t)(n0 + row) * H_DIM + kc * 8;
  }

  f32x4 b1v[2][2], b3v[2][2];   // next-tile B held in regs (loop-carried)

#define ISSUE_A1(buf, koff)                                               \
  { _Pragma("unroll") for (int q = 0; q < 8; ++q)                         \
      gld16(asrc[q] + (koff), &lsA[buf][(q * 256 + tid) * 8]); }

#define LOAD_B1(koff)                                                     \
  { _Pragma("unroll") for (int q = 0; q < 2; ++q) {                       \
      b1v[q][0] = *(const f32x4*)(b1src[q] + (koff));                     \
      b1v[q][1] = *(const f32x4*)(b1src[q] + (koff) + 4);                 \
      b3v[q][0] = *(const f32x4*)(b3src[q] + (koff));                     \
      b3v[q][1] = *(const f32x4*)(b3src[q] + (koff) + 4);                 \
    } }

#define CVTW_B1()                                                         \
  { _Pragma("unroll") for (int q = 0; q < 2; ++q) {                       \
      u16x8 ob1, ob3;                                                     \
      _Pragma("unroll") for (int j = 0; j < 4; ++j) {                     \
        ob1[j] = f2bf(b1v[q][0][j]); ob1[j + 4] = f2bf(b1v[q][1][j]);     \
        ob3[j] = f2bf(b3v[q][0][j]); ob3[j + 4] = f2bf(b3v[q][1][j]);     \
      }                                                                   \
      *(u16x8*)&lsB1[bdst[q]] = ob1;                                      \
      *(u16x8*)&lsB3[bdst[q]] = ob3;                                      \
    } }

  const f32x4 fz = {0.f, 0.f, 0.f, 0.f};
  f32x4 acc1[8][2], acc3[8][2];
#pragma unroll
  for (int i = 0; i < 8; ++i)
#pragma unroll
    for (int j = 0; j < 2; ++j) { acc1[i][j] = fz; acc3[i][j] = fz; }

  const int NT = H_DIM / 64;   // 16
  // prologue: tile0 staged (A0 in flight gets drained by the B0 cvt's vmcnt),
  // tile1 issued (A->buf1, B->regs)
  ISSUE_A1(0, 0)
  LOAD_B1(0)
  CVTW_B1()
  ISSUE_A1(1, 64)
  LOAD_B1(64)
  FENCE();

  for (int t = 0; t < NT; ++t) {
    const int cur = t & 1;
    asm volatile("s_waitcnt lgkmcnt(0)" ::: "memory");  // own B ds_writes done
    __builtin_amdgcn_s_barrier();
    FENCE();
    __builtin_amdgcn_s_setprio(1);
#pragma unroll
    for (int ks = 0; ks < 2; ++ks) {
      const int kg = ks * 4 + (lane >> 4);
      bf16x8 af[8], b1f[2], b3f[2];
#pragma unroll
      for (int i = 0; i < 8; ++i) {
        const int ar = wm + i * 16 + (lane & 15);
        af[i] = *(const bf16x8*)&lsA[cur][ar * 64 + ((kg ^ (ar & 7)) * 8)];
      }
#pragma unroll
      for (int j = 0; j < 2; ++j) {
        const int br = wn + j * 16 + (lane & 15);
        b1f[j] = *(const bf16x8*)&lsB1[br * 64 + ((kg ^ (br & 7)) * 8)];
        b3f[j] = *(const bf16x8*)&lsB3[br * 64 + ((kg ^ (br & 7)) * 8)];
      }
#pragma unroll
      for (int i = 0; i < 8; ++i)
#pragma unroll
        for (int j = 0; j < 2; ++j) {
          acc1[i][j] = __builtin_amdgcn_mfma_f32_16x16x32_bf16(af[i], b1f[j], acc1[i][j], 0, 0, 0);
          acc3[i][j] = __builtin_amdgcn_mfma_f32_16x16x32_bf16(af[i], b3f[j], acc3[i][j], 0, 0, 0);
        }
    }
    __builtin_amdgcn_s_setprio(0);
    FENCE();
    __builtin_amdgcn_s_barrier();   // all waves done reading lsA[cur], lsB1/3
    FENCE();
    if (t + 1 < NT) {
      CVTW_B1()                     // write B(t+1); compiler vmcnt drains loads
      if (t + 2 < NT) {
        ISSUE_A1(cur, (t + 2) * 64) // refill the A buffer just freed
        LOAD_B1((t + 2) * 64)       // B(t+2) -> regs, flies under COMPUTE(t+1)
      }
    }
  }
#undef ISSUE_A1
#undef LOAD_B1
#undef CVTW_B1

  // epilogue: h = g * silu(a1) * a3 -> bf16. C/D: col=lane&15, row=(lane>>4)*4+r
  const int be = base[e];
#pragma unroll
  for (int i = 0; i < 8; ++i) {
#pragma unroll
    for (int r = 0; r < 4; ++r) {
      const int lrow = m0 + wm + i * 16 + (lane >> 4) * 4 + r;
      if (lrow < cnte) {
        const float g = pairGate[e * T_TOK + lrow];
        uint16_t* hp = hbuf + (size_t)(be + lrow) * F_DIM + n0 + wn + (lane & 15);
#pragma unroll
        for (int j = 0; j < 2; ++j) {
          const float a  = acc1[i][j][r];
          const float hv = g * (a / (1.f + __expf(-a))) * acc3[i][j][r];
          hp[j * 16] = f2bf(hv);
        }
      }
    }
  }
}

// ---------------- stage 2: y[row] = h[row] @ w2^T  (bf16 stores, no atomics)
// R9 geometry (BM=256 x BN=128, 256 thr, wave 128x64, acc[8][4]); same T14
// async-split + A-dbuf structure. LDS = 2x32K (A) + 16K (B) = 80 KB.
__global__ __launch_bounds__(256, 2) void ffn2_k(
    const uint16_t* __restrict__ hbuf, const float* __restrict__ w2,
    uint16_t* __restrict__ y, const int* __restrict__ cnt,
    const int* __restrict__ base)
{
  const int mg0 = blockIdx.y * 256;
  if (mg0 >= base[NE]) return;
  int e = 0;
#pragma unroll
  for (int k = 1; k < NE; ++k) if (mg0 >= base[k]) e = k;
  const int m0   = mg0 - base[e];
  const int cnte = cnt[e];
  const int n0   = blockIdx.x * 128;
  const int tid  = threadIdx.x;
  const int lane = tid & 63;
  const int wid  = tid >> 6;
  const int wm   = (wid >> 1) * 128;   // 0 or 128
  const int wn   = (wid & 1) * 64;     // 0 or 64

  __shared__ __align__(16) uint16_t lsA[2][256 * 64];   // 64 KB
  __shared__ __align__(16) uint16_t lsB[128 * 64];      // 16 KB

  const int be = base[e];
  const float* w2e = w2 + (size_t)e * H_DIM * F_DIM;

  const uint16_t* asrc[8];
#pragma unroll
  for (int q = 0; q < 8; ++q) {
    const int c = q * 256 + tid;
    const int row = c >> 3, pos = c & 7;
    const int kc  = pos ^ (row & 7);
    int rr = m0 + row; if (rr >= cnte) rr = cnte - 1;
    asrc[q] = hbuf + (size_t)(be + rr) * F_DIM + kc * 8;
  }
  const float* bsrc[4];
  int bdst[4];
#pragma unroll
  for (int q = 0; q < 4; ++q) {
    const int c = q * 256 + tid;
    const int row = c >> 3, pos = c & 7;
    const int kc  = pos ^ (row & 7);
    bdst[q] = c * 8;
    bsrc[q] = w2e + (size_t)(n0 + row) * F_DIM + kc * 8;
  }

  f32x4 bv[4][2];   // next-tile B in regs

#define ISSUE_A2(buf, koff)                                               \
  { _Pragma("unroll") for (int q = 0; q < 8; ++q)                         \
      gld16(asrc[q] + (koff), &lsA[buf][(q * 256 + tid) * 8]); }

#define LOAD_B2(koff)                                                     \
  { _Pragma("unroll") for (int q = 0; q < 4; ++q) {                       \
      bv[q][0] = *(const f32x4*)(bsrc[q] + (koff));                       \
      bv[q][1] = *(const f32x4*)(bsrc[q] + (koff) + 4);                   \
    } }

#define CVTW_B2()                                                         \
  { _Pragma("unroll") for (int q = 0; q < 4; ++q) {                       \
      u16x8 ob;                                                           \
      _Pragma("unroll") for (int j = 0; j < 4; ++j) {                     \
        ob[j] = f2bf(bv[q][0][j]); ob[j + 4] = f2bf(bv[q][1][j]);         \
      }                                                                   \
      *(u16x8*)&lsB[bdst[q]] = ob;                                        \
    } }

  const f32x4 fz = {0.f, 0.f, 0.f, 0.f};
  f32x4 acc[8][4];
#pragma unroll
  for (int i = 0; i < 8; ++i)
#pragma unroll
    for (int j = 0; j < 4; ++j) acc[i][j] = fz;

  const int NT = F_DIM / 64;   // 64
  ISSUE_A2(0, 0)
  LOAD_B2(0)
  CVTW_B2()
  ISSUE_A2(1, 64)
  LOAD_B2(64)
  FENCE();

  for (int t = 0; t < NT; ++t) {
    const int cur = t & 1;
    asm volatile("s_waitcnt lgkmcnt(0)" ::: "memory");
    __builtin_amdgcn_s_barrier();
    FENCE();
    __builtin_amdgcn_s_setprio(1);
#pragma unroll
    for (int ks = 0; ks < 2; ++ks) {
      const int kg = ks * 4 + (lane >> 4);
      bf16x8 af[8], bf[4];
#pragma unroll
      for (int i = 0; i < 8; ++i) {
        const int ar = wm + i * 16 + (lane & 15);
        af[i] = *(const bf16x8*)&lsA[cur][ar * 64 + ((kg ^ (ar & 7)) * 8)];
      }
#pragma unroll
      for (int j = 0; j < 4; ++j) {
        const int br = wn + j * 16 + (lane & 15);
        bf[j] = *(const bf16x8*)&lsB[br * 64 + ((kg ^ (br & 7)) * 8)];
      }
#pragma unroll
      for (int i = 0; i < 8; ++i)
#pragma unroll
        for (int j = 0; j < 4; ++j)
          acc[i][j] = __builtin_amdgcn_mfma_f32_16x16x32_bf16(af[i], bf[j], acc[i][j], 0, 0, 0);
    }
    __builtin_amdgcn_s_setprio(0);
    FENCE();
    __builtin_amdgcn_s_barrier();
    FENCE();
    if (t + 1 < NT) {
      CVTW_B2()
      if (t + 2 < NT) {
        ISSUE_A2(cur, (t + 2) * 64)
        LOAD_B2((t + 2) * 64)
      }
    }
  }
#undef ISSUE_A2
#undef LOAD_B2
#undef CVTW_B2

  // epilogue: plain bf16 stores into pair-row buffer (gate already in h)
#pragma unroll
  for (int i = 0; i < 8; ++i) {
#pragma unroll
    for (int r = 0; r < 4; ++r) {
      const int lrow = m0 + wm + i * 16 + (lane >> 4) * 4 + r;
      if (lrow < cnte) {
        uint16_t* yp = y + (size_t)(be + lrow) * H_DIM + n0 + wn + (lane & 15);
#pragma unroll
        for (int j = 0; j < 4; ++j)
          yp[j * 16] = f2bf(acc[i][j][r]);
      }
    }
  }
}

// ---------------- combine: out[t] = y[slot1(t)] + y[slot2(t)]  (fp32 out)
__global__ __launch_bounds__(256) void combine_k(
    const uint16_t* __restrict__ y, const int* __restrict__ tokSlot,
    const int* __restrict__ base, float* __restrict__ out)
{
  const int t = blockIdx.x * 2 + (threadIdx.x >> 7);
  const int c = (threadIdx.x & 127) * 8;
  const int4 s = ((const int4*)tokSlot)[t];
  const uint16_t* y1 = y + (size_t)(base[s.x] + s.y) * H_DIM + c;
  const uint16_t* y2 = y + (size_t)(base[s.z] + s.w) * H_DIM + c;
  const u16x8 a = *(const u16x8*)y1;
  const u16x8 b = *(const u16x8*)y2;
  float* op = out + (size_t)t * H_DIM + c;
  f32x4 o0, o1;
#pragma unroll
  for (int j = 0; j < 4; ++j) {
    o0[j] = __bfloat162float(__hip_bfloat16_raw{a[j]}) +
            __bfloat162float(__hip_bfloat16_raw{b[j]});
    o1[j] = __bfloat162float(__hip_bfloat16_raw{a[j + 4]}) +
            __bfloat162float(__hip_bfloat16_raw{b[j + 4]});
  }
  *(f32x4*)op       = o0;
  *(f32x4*)(op + 4) = o1;
}

extern "C" void kernel_launch(void* const* d_in, const int* in_sizes, int n_in,
                              void* d_out, int out_size, void* d_ws, size_t ws_size,
                              hipStream_t stream)
{
  const float* x  = (const float*)d_in[0];
  const float* wr = (const float*)d_in[1];
  const float* w1 = (const float*)d_in[2];
  const float* w2 = (const float*)d_in[3];
  const float* w3 = (const float*)d_in[4];
  float* out    = (float*)d_out;
  float* logits = out + (size_t)T_TOK * H_DIM;

  uint8_t* ws = (uint8_t*)d_ws;
  const size_t PADROWS  = (size_t)MG_BLKS * 256;                    // 10240
  const size_t XB_OFF   = 0;
  const size_t HB_OFF   = XB_OFF + (size_t)T_TOK * H_DIM * 2;       // 8 MB
  const size_t Y_OFF    = HB_OFF + PADROWS * F_DIM * 2;             // +80 MB
  const size_t PT_OFF   = Y_OFF + PADROWS * H_DIM * 2;              // +20 MB
  const size_t PG_OFF   = PT_OFF + (size_t)NE * T_TOK * 4;
  const size_t TS_OFF   = PG_OFF + (size_t)NE * T_TOK * 4;
  const size_t CNT_OFF  = TS_OFF + (size_t)T_TOK * 16;
  const size_t BASE_OFF = CNT_OFF + 64;
  const size_t NEED     = BASE_OFF + 64;
  if (ws_size < NEED) return;

  uint16_t* xb      = (uint16_t*)(ws + XB_OFF);
  uint16_t* hb      = (uint16_t*)(ws + HB_OFF);
  uint16_t* yb      = (uint16_t*)(ws + Y_OFF);
  int*      pairTok = (int*)(ws + PT_OFF);
  float*    pairGate= (float*)(ws + PG_OFF);
  int*      tokSlot = (int*)(ws + TS_OFF);
  int*      cnt     = (int*)(ws + CNT_OFF);
  int*      basep   = (int*)(ws + BASE_OFF);

  hipMemsetAsync(cnt, 0, 64, stream);
  router_k<<<T_TOK / 4, 256, 0, stream>>>(x, wr, logits, xb, pairTok, pairGate, tokSlot, cnt);
  prefix_k<<<1, 64, 0, stream>>>(cnt, basep);
  ffn1_k<<<dim3(F_DIM / 64, MG_BLKS, 1), 256, 0, stream>>>(xb, w1, w3, hb, pairTok, pairGate, cnt, basep);
  ffn2_k<<<dim3(H_DIM / 128, MG_BLKS, 1), 256, 0, stream>>>(hb, w2, yb, cnt, basep);
  combine_k<<<T_TOK / 2, 256, 0, stream>>>(yb, tokSlot, basep, out);
}

// Round 13
// 468.437 us; speedup vs baseline: 1.1581x; 1.0031x over previous
//
#include <hip/hip_runtime.h>
#include <hip/hip_bf16.h>
#include <stdint.h>

#define T_TOK 4096
#define H_DIM 1024
#define F_DIM 4096
#define NE 8
#define MG_BLKS 40   // ceil((2T + 8*255)/256): max 256-aligned m-chunks

typedef float    f32x4  __attribute__((ext_vector_type(4)));
typedef __bf16   bf16x8 __attribute__((ext_vector_type(8)));
typedef uint16_t u16x8  __attribute__((ext_vector_type(8)));

#define AS1 __attribute__((address_space(1)))
#define AS3 __attribute__((address_space(3)))

__device__ __forceinline__ uint16_t f2bf(float f) {
  return __builtin_bit_cast(uint16_t, __float2bfloat16(f));
}

__device__ __forceinline__ void gld16(const void* g, void* l) {
  __builtin_amdgcn_global_load_lds((const AS1 void*)g, (AS3 void*)l, 16, 0, 0);
}

// read 8 consecutive k-elements of a fp32 LDS tile (16B-chunk XOR swizzled),
// convert to bf16x8 fragment
__device__ __forceinline__ bf16x8 ldsB_frag(const float* tile, int row, int kg) {
  const int p0 = (2 * kg) ^ (row & 15);
  const int p1 = (2 * kg + 1) ^ (row & 15);
  const f32x4 v0 = *(const f32x4*)&tile[row * 64 + p0 * 4];
  const f32x4 v1 = *(const f32x4*)&tile[row * 64 + p1 * 4];
  u16x8 ub;
#pragma unroll
  for (int j = 0; j < 4; ++j) { ub[j] = f2bf(v0[j]); ub[j + 4] = f2bf(v1[j]); }
  return __builtin_bit_cast(bf16x8, ub);
}

// ---------------- router: logits (fp32, exact), top-2 gates, compaction, x->bf16
__global__ __launch_bounds__(256) void router_k(
    const float* __restrict__ x, const float* __restrict__ wr,
    float* __restrict__ logits, uint16_t* __restrict__ xb,
    int* __restrict__ pairTok, float* __restrict__ pairGate,
    int* __restrict__ tokSlot, int* __restrict__ cnt)
{
  const int lane = threadIdx.x & 63;
  const int wid  = threadIdx.x >> 6;
  const int t    = blockIdx.x * 4 + wid;

  const float* xp = x + (size_t)t * H_DIM + lane * 16;
  f32x4 xv[4];
#pragma unroll
  for (int i = 0; i < 4; ++i) xv[i] = *(const f32x4*)(xp + 4 * i);

  u16x8 o0, o1;
#pragma unroll
  for (int j = 0; j < 4; ++j) {
    o0[j] = f2bf(xv[0][j]); o0[j + 4] = f2bf(xv[1][j]);
    o1[j] = f2bf(xv[2][j]); o1[j + 4] = f2bf(xv[3][j]);
  }
  uint16_t* xbp = xb + (size_t)t * H_DIM + lane * 16;
  *(u16x8*)xbp       = o0;
  *(u16x8*)(xbp + 8) = o1;

  float s[NE];
#pragma unroll
  for (int e = 0; e < NE; ++e) {
    const float* wp = wr + e * H_DIM + lane * 16;
    float acc = 0.f;
#pragma unroll
    for (int i = 0; i < 4; ++i) {
      f32x4 wv = *(const f32x4*)(wp + 4 * i);
#pragma unroll
      for (int j = 0; j < 4; ++j) acc += xv[i][j] * wv[j];
    }
#pragma unroll
    for (int off = 32; off > 0; off >>= 1) acc += __shfl_xor(acc, off, 64);
    s[e] = acc;
  }

  if (lane == 0) {
#pragma unroll
    for (int e = 0; e < NE; ++e) logits[t * NE + e] = s[e];
    int e1 = 0;
#pragma unroll
    for (int e = 1; e < NE; ++e) if (s[e] > s[e1]) e1 = e;
    int e2 = (e1 == 0) ? 1 : 0;
#pragma unroll
    for (int e = 0; e < NE; ++e)
      if (e != e1 && e != e2 && s[e] > s[e2]) e2 = e;
    const float d  = s[e2] - s[e1];              // <= 0
    const float g1 = 1.f / (1.f + __expf(d));
    const float g2 = 1.f - g1;
    int i1 = atomicAdd(cnt + e1, 1);
    pairTok[e1 * T_TOK + i1] = t;  pairGate[e1 * T_TOK + i1] = g1;
    int i2 = atomicAdd(cnt + e2, 1);
    pairTok[e2 * T_TOK + i2] = t;  pairGate[e2 * T_TOK + i2] = g2;
    int4 sl; sl.x = e1; sl.y = i1; sl.z = e2; sl.w = i2;
    ((int4*)tokSlot)[t] = sl;
  }
}

// ---------------- prefix: 256-aligned bases; base[NE] = padded total
__global__ void prefix_k(const int* __restrict__ cnt, int* __restrict__ base) {
  if (threadIdx.x == 0) {
    int b = 0;
#pragma unroll
    for (int e = 0; e < NE; ++e) { base[e] = b; b += (cnt[e] + 255) & ~255; }
    base[NE] = b;
  }
}

// ---------------- stage 1: h = gate * silu(x@w1^T) * (x@w3^T)
// R9 geometry (BM=256 x BN=64, BK=64, 256 thr, 4 waves, wave 128x32, dual acc).
// NEW: B staged as RAW FP32 via global_load_lds (pure async, no reg round-trip,
// no ds_write, no cvt pass); bf16 conversion at fragment read. LDS 64 KB.
__global__ __launch_bounds__(256, 2) void ffn1_k(
    const uint16_t* __restrict__ xb, const float* __restrict__ w1,
    const float* __restrict__ w3, uint16_t* __restrict__ hbuf,
    const int* __restrict__ pairTok, const float* __restrict__ pairGate,
    const int* __restrict__ cnt, const int* __restrict__ base)
{
  const int mg0 = blockIdx.y * 256;
  if (mg0 >= base[NE]) return;
  int e = 0;
#pragma unroll
  for (int k = 1; k < NE; ++k) if (mg0 >= base[k]) e = k;
  const int m0   = mg0 - base[e];
  const int cnte = cnt[e];
  const int n0   = blockIdx.x * 64;
  const int tid  = threadIdx.x;
  const int lane = tid & 63;
  const int wid  = tid >> 6;
  const int wm   = (wid >> 1) * 128;   // 0 or 128
  const int wn   = (wid & 1) * 32;     // 0 or 32

  __shared__ __align__(16) uint16_t lsA [256 * 64];  // 32 KB bf16
  __shared__ __align__(16) float    lsB1[ 64 * 64];  // 16 KB fp32
  __shared__ __align__(16) float    lsB3[ 64 * 64];  // 16 KB fp32

  const float* w1e = w1 + (size_t)e * F_DIM * H_DIM;
  const float* w3e = w3 + (size_t)e * F_DIM * H_DIM;

  // A: 2048 16B-chunks (8 bf16), 8/thread; chunk c: row=c>>3, pos=c&7, kc=pos^(row&7)
  const uint16_t* asrc[8];
#pragma unroll
  for (int q = 0; q < 8; ++q) {
    const int c = q * 256 + tid;
    const int row = c >> 3, pos = c & 7;
    const int kc  = pos ^ (row & 7);
    int ar = m0 + row; if (ar >= cnte) ar = cnte - 1;
    const int tok = pairTok[e * T_TOK + ar];
    asrc[q] = xb + (size_t)tok * H_DIM + kc * 8;
  }
  // B (fp32): 64 rows x 16 chunks of 16B (4 f32); 1024 chunks each, 4/thread.
  // chunk c: row=c>>4, pos=c&15, source chunk kc=pos^(row&15)
  const float* b1src[4];
  const float* b3src[4];
#pragma unroll
  for (int q = 0; q < 4; ++q) {
    const int c = q * 256 + tid;
    const int row = c >> 4, pos = c & 15;
    const int kc  = pos ^ (row & 15);
    b1src[q] = w1e + (size_t)(n0 + row) * H_DIM + kc * 4;
    b3src[q] = w3e + (size_t)(n0 + row) * H_DIM + kc * 4;
  }

  const f32x4 fz = {0.f, 0.f, 0.f, 0.f};
  f32x4 acc1[8][2], acc3[8][2];
#pragma unroll
  for (int i = 0; i < 8; ++i)
#pragma unroll
    for (int j = 0; j < 2; ++j) { acc1[i][j] = fz; acc3[i][j] = fz; }

  for (int kt = 0; kt < H_DIM; kt += 64) {
    __syncthreads();
#pragma unroll
    for (int q = 0; q < 8; ++q)
      gld16(asrc[q] + kt, &lsA[(q * 256 + tid) * 8]);
#pragma unroll
    for (int q = 0; q < 4; ++q) {
      gld16(b1src[q] + kt, &lsB1[(q * 256 + tid) * 4]);
      gld16(b3src[q] + kt, &lsB3[(q * 256 + tid) * 4]);
    }
    __syncthreads();
#pragma unroll
    for (int ks = 0; ks < 2; ++ks) {
      const int kg = ks * 4 + (lane >> 4);
      bf16x8 af[8], b1f[2], b3f[2];
#pragma unroll
      for (int i = 0; i < 8; ++i) {
        const int ar = wm + i * 16 + (lane & 15);
        af[i] = *(const bf16x8*)&lsA[ar * 64 + ((kg ^ (ar & 7)) * 8)];
      }
#pragma unroll
      for (int j = 0; j < 2; ++j) {
        const int br = wn + j * 16 + (lane & 15);
        b1f[j] = ldsB_frag(lsB1, br, kg);
        b3f[j] = ldsB_frag(lsB3, br, kg);
      }
#pragma unroll
      for (int i = 0; i < 8; ++i)
#pragma unroll
        for (int j = 0; j < 2; ++j) {
          acc1[i][j] = __builtin_amdgcn_mfma_f32_16x16x32_bf16(af[i], b1f[j], acc1[i][j], 0, 0, 0);
          acc3[i][j] = __builtin_amdgcn_mfma_f32_16x16x32_bf16(af[i], b3f[j], acc3[i][j], 0, 0, 0);
        }
    }
  }

  // epilogue: h = g * silu(a1) * a3 -> bf16. C/D: col=lane&15, row=(lane>>4)*4+r
  const int be = base[e];
#pragma unroll
  for (int i = 0; i < 8; ++i) {
#pragma unroll
    for (int r = 0; r < 4; ++r) {
      const int lrow = m0 + wm + i * 16 + (lane >> 4) * 4 + r;
      if (lrow < cnte) {
        const float g = pairGate[e * T_TOK + lrow];
        uint16_t* hp = hbuf + (size_t)(be + lrow) * F_DIM + n0 + wn + (lane & 15);
#pragma unroll
        for (int j = 0; j < 2; ++j) {
          const float a  = acc1[i][j][r];
          const float hv = g * (a / (1.f + __expf(-a))) * acc3[i][j][r];
          hp[j * 16] = f2bf(hv);
        }
      }
    }
  }
}

// ---------------- stage 2: y[row] = h[row] @ w2^T  (bf16 stores, no atomics)
// R9 geometry (BM=256 x BN=128, 256 thr, wave 128x64, acc[8][4]); B raw fp32
// via gld16, cvt at fragment read. LDS = A 32K + B 32K = 64 KB.
__global__ __launch_bounds__(256, 2) void ffn2_k(
    const uint16_t* __restrict__ hbuf, const float* __restrict__ w2,
    uint16_t* __restrict__ y, const int* __restrict__ cnt,
    const int* __restrict__ base)
{
  const int mg0 = blockIdx.y * 256;
  if (mg0 >= base[NE]) return;
  int e = 0;
#pragma unroll
  for (int k = 1; k < NE; ++k) if (mg0 >= base[k]) e = k;
  const int m0   = mg0 - base[e];
  const int cnte = cnt[e];
  const int n0   = blockIdx.x * 128;
  const int tid  = threadIdx.x;
  const int lane = tid & 63;
  const int wid  = tid >> 6;
  const int wm   = (wid >> 1) * 128;   // 0 or 128
  const int wn   = (wid & 1) * 64;     // 0 or 64

  __shared__ __align__(16) uint16_t lsA[256 * 64];   // 32 KB bf16
  __shared__ __align__(16) float    lsB[128 * 64];   // 32 KB fp32

  const int be = base[e];
  const float* w2e = w2 + (size_t)e * H_DIM * F_DIM;

  const uint16_t* asrc[8];
#pragma unroll
  for (int q = 0; q < 8; ++q) {
    const int c = q * 256 + tid;
    const int row = c >> 3, pos = c & 7;
    const int kc  = pos ^ (row & 7);
    int rr = m0 + row; if (rr >= cnte) rr = cnte - 1;
    asrc[q] = hbuf + (size_t)(be + rr) * F_DIM + kc * 8;
  }
  // B (fp32): 128 rows x 16 chunks; 2048 chunks, 8/thread
  const float* bsrc[8];
#pragma unroll
  for (int q = 0; q < 8; ++q) {
    const int c = q * 256 + tid;
    const int row = c >> 4, pos = c & 15;
    const int kc  = pos ^ (row & 15);
    bsrc[q] = w2e + (size_t)(n0 + row) * F_DIM + kc * 4;
  }

  const f32x4 fz = {0.f, 0.f, 0.f, 0.f};
  f32x4 acc[8][4];
#pragma unroll
  for (int i = 0; i < 8; ++i)
#pragma unroll
    for (int j = 0; j < 4; ++j) acc[i][j] = fz;

  for (int kt = 0; kt < F_DIM; kt += 64) {
    __syncthreads();
#pragma unroll
    for (int q = 0; q < 8; ++q)
      gld16(asrc[q] + kt, &lsA[(q * 256 + tid) * 8]);
#pragma unroll
    for (int q = 0; q < 8; ++q)
      gld16(bsrc[q] + kt, &lsB[(q * 256 + tid) * 4]);
    __syncthreads();
#pragma unroll
    for (int ks = 0; ks < 2; ++ks) {
      const int kg = ks * 4 + (lane >> 4);
      bf16x8 af[8], bf[4];
#pragma unroll
      for (int i = 0; i < 8; ++i) {
        const int ar = wm + i * 16 + (lane & 15);
        af[i] = *(const bf16x8*)&lsA[ar * 64 + ((kg ^ (ar & 7)) * 8)];
      }
#pragma unroll
      for (int j = 0; j < 4; ++j) {
        const int br = wn + j * 16 + (lane & 15);
        bf[j] = ldsB_frag(lsB, br, kg);
      }
#pragma unroll
      for (int i = 0; i < 8; ++i)
#pragma unroll
        for (int j = 0; j < 4; ++j)
          acc[i][j] = __builtin_amdgcn_mfma_f32_16x16x32_bf16(af[i], bf[j], acc[i][j], 0, 0, 0);
    }
  }

  // epilogue: plain bf16 stores into pair-row buffer (gate already in h)
#pragma unroll
  for (int i = 0; i < 8; ++i) {
#pragma unroll
    for (int r = 0; r < 4; ++r) {
      const int lrow = m0 + wm + i * 16 + (lane >> 4) * 4 + r;
      if (lrow < cnte) {
        uint16_t* yp = y + (size_t)(be + lrow) * H_DIM + n0 + wn + (lane & 15);
#pragma unroll
        for (int j = 0; j < 4; ++j)
          yp[j * 16] = f2bf(acc[i][j][r]);
      }
    }
  }
}

// ---------------- combine: out[t] = y[slot1(t)] + y[slot2(t)]  (fp32 out)
__global__ __launch_bounds__(256) void combine_k(
    const uint16_t* __restrict__ y, const int* __restrict__ tokSlot,
    const int* __restrict__ base, float* __restrict__ out)
{
  const int t = blockIdx.x * 2 + (threadIdx.x >> 7);
  const int c = (threadIdx.x & 127) * 8;
  const int4 s = ((const int4*)tokSlot)[t];
  const uint16_t* y1 = y + (size_t)(base[s.x] + s.y) * H_DIM + c;
  const uint16_t* y2 = y + (size_t)(base[s.z] + s.w) * H_DIM + c;
  const u16x8 a = *(const u16x8*)y1;
  const u16x8 b = *(const u16x8*)y2;
  float* op = out + (size_t)t * H_DIM + c;
  f32x4 o0, o1;
#pragma unroll
  for (int j = 0; j < 4; ++j) {
    o0[j] = __bfloat162float(__hip_bfloat16_raw{a[j]}) +
            __bfloat162float(__hip_bfloat16_raw{b[j]});
    o1[j] = __bfloat162float(__hip_bfloat16_raw{a[j + 4]}) +
            __bfloat162float(__hip_bfloat16_raw{b[j + 4]});
  }
  *(f32x4*)op       = o0;
  *(f32x4*)(op + 4) = o1;
}

extern "C" void kernel_launch(void* const* d_in, const int* in_sizes, int n_in,
                              void* d_out, int out_size, void* d_ws, size_t ws_size,
                              hipStream_t stream)
{
  const float* x  = (const float*)d_in[0];
  const float* wr = (const float*)d_in[1];
  const float* w1 = (const float*)d_in[2];
  const float* w2 = (const float*)d_in[3];
  const float* w3 = (const float*)d_in[4];
  float* out    = (float*)d_out;
  float* logits = out + (size_t)T_TOK * H_DIM;

  uint8_t* ws = (uint8_t*)d_ws;
  const size_t PADROWS  = (size_t)MG_BLKS * 256;                    // 10240
  const size_t XB_OFF   = 0;
  const size_t HB_OFF   = XB_OFF + (size_t)T_TOK * H_DIM * 2;       // 8 MB
  const size_t Y_OFF    = HB_OFF + PADROWS * F_DIM * 2;             // +80 MB
  const size_t PT_OFF   = Y_OFF + PADROWS * H_DIM * 2;              // +20 MB
  const size_t PG_OFF   = PT_OFF + (size_t)NE * T_TOK * 4;
  const size_t TS_OFF   = PG_OFF + (size_t)NE * T_TOK * 4;
  const size_t CNT_OFF  = TS_OFF + (size_t)T_TOK * 16;
  const size_t BASE_OFF = CNT_OFF + 64;
  const size_t NEED     = BASE_OFF + 64;
  if (ws_size < NEED) return;

  uint16_t* xb      = (uint16_t*)(ws + XB_OFF);
  uint16_t* hb      = (uint16_t*)(ws + HB_OFF);
  uint16_t* yb      = (uint16_t*)(ws + Y_OFF);
  int*      pairTok = (int*)(ws + PT_OFF);
  float*    pairGate= (float*)(ws + PG_OFF);
  int*      tokSlot = (int*)(ws + TS_OFF);
  int*      cnt     = (int*)(ws + CNT_OFF);
  int*      basep   = (int*)(ws + BASE_OFF);

  hipMemsetAsync(cnt, 0, 64, stream);
  router_k<<<T_TOK / 4, 256, 0, stream>>>(x, wr, logits, xb, pairTok, pairGate, tokSlot, cnt);
  prefix_k<<<1, 64, 0, stream>>>(cnt, basep);
  ffn1_k<<<dim3(F_DIM / 64, MG_BLKS, 1), 256, 0, stream>>>(xb, w1, w3, hb, pairTok, pairGate, cnt, basep);
  ffn2_k<<<dim3(H_DIM / 128, MG_BLKS, 1), 256, 0, stream>>>(hb, w2, yb, cnt, basep);
  combine_k<<<T_TOK / 2, 256, 0, stream>>>(yb, tokSlot, basep, out);
}

// Round 14
// 465.444 us; speedup vs baseline: 1.1655x; 1.0064x over previous
//
#include <hip/hip_runtime.h>
#include <hip/hip_bf16.h>
#include <stdint.h>

#define T_TOK 4096
#define H_DIM 1024
#define F_DIM 4096
#define NE 8
#define MG_BLKS 40   // ceil((2T + 8*255)/256): max 256-aligned m-chunks

typedef float    f32x4  __attribute__((ext_vector_type(4)));
typedef __bf16   bf16x8 __attribute__((ext_vector_type(8)));
typedef uint16_t u16x8  __attribute__((ext_vector_type(8)));

#define AS1 __attribute__((address_space(1)))
#define AS3 __attribute__((address_space(3)))

__device__ __forceinline__ uint16_t f2bf(float f) {
  return __builtin_bit_cast(uint16_t, __float2bfloat16(f));
}

__device__ __forceinline__ void gld16(const void* g, void* l) {
  __builtin_amdgcn_global_load_lds((const AS1 void*)g, (AS3 void*)l, 16, 0, 0);
}

// read 8 consecutive k-elements of a fp32 LDS tile (16B-chunk XOR swizzled),
// convert to bf16x8 fragment
__device__ __forceinline__ bf16x8 ldsB_frag(const float* tile, int row, int kg) {
  const int p0 = (2 * kg) ^ (row & 15);
  const int p1 = (2 * kg + 1) ^ (row & 15);
  const f32x4 v0 = *(const f32x4*)&tile[row * 64 + p0 * 4];
  const f32x4 v1 = *(const f32x4*)&tile[row * 64 + p1 * 4];
  u16x8 ub;
#pragma unroll
  for (int j = 0; j < 4; ++j) { ub[j] = f2bf(v0[j]); ub[j + 4] = f2bf(v1[j]); }
  return __builtin_bit_cast(bf16x8, ub);
}

// ---------------- router: logits (fp32, exact), top-2 gates, compaction, x->bf16
__global__ __launch_bounds__(256) void router_k(
    const float* __restrict__ x, const float* __restrict__ wr,
    float* __restrict__ logits, uint16_t* __restrict__ xb,
    int* __restrict__ pairTok, float* __restrict__ pairGate,
    int* __restrict__ tokSlot, int* __restrict__ cnt)
{
  const int lane = threadIdx.x & 63;
  const int wid  = threadIdx.x >> 6;
  const int t    = blockIdx.x * 4 + wid;

  const float* xp = x + (size_t)t * H_DIM + lane * 16;
  f32x4 xv[4];
#pragma unroll
  for (int i = 0; i < 4; ++i) xv[i] = *(const f32x4*)(xp + 4 * i);

  u16x8 o0, o1;
#pragma unroll
  for (int j = 0; j < 4; ++j) {
    o0[j] = f2bf(xv[0][j]); o0[j + 4] = f2bf(xv[1][j]);
    o1[j] = f2bf(xv[2][j]); o1[j + 4] = f2bf(xv[3][j]);
  }
  uint16_t* xbp = xb + (size_t)t * H_DIM + lane * 16;
  *(u16x8*)xbp       = o0;
  *(u16x8*)(xbp + 8) = o1;

  float s[NE];
#pragma unroll
  for (int e = 0; e < NE; ++e) {
    const float* wp = wr + e * H_DIM + lane * 16;
    float acc = 0.f;
#pragma unroll
    for (int i = 0; i < 4; ++i) {
      f32x4 wv = *(const f32x4*)(wp + 4 * i);
#pragma unroll
      for (int j = 0; j < 4; ++j) acc += xv[i][j] * wv[j];
    }
#pragma unroll
    for (int off = 32; off > 0; off >>= 1) acc += __shfl_xor(acc, off, 64);
    s[e] = acc;
  }

  if (lane == 0) {
#pragma unroll
    for (int e = 0; e < NE; ++e) logits[t * NE + e] = s[e];
    int e1 = 0;
#pragma unroll
    for (int e = 1; e < NE; ++e) if (s[e] > s[e1]) e1 = e;
    int e2 = (e1 == 0) ? 1 : 0;
#pragma unroll
    for (int e = 0; e < NE; ++e)
      if (e != e1 && e != e2 && s[e] > s[e2]) e2 = e;
    const float d  = s[e2] - s[e1];              // <= 0
    const float g1 = 1.f / (1.f + __expf(d));
    const float g2 = 1.f - g1;
    int i1 = atomicAdd(cnt + e1, 1);
    pairTok[e1 * T_TOK + i1] = t;  pairGate[e1 * T_TOK + i1] = g1;
    int i2 = atomicAdd(cnt + e2, 1);
    pairTok[e2 * T_TOK + i2] = t;  pairGate[e2 * T_TOK + i2] = g2;
    int4 sl; sl.x = e1; sl.y = i1; sl.z = e2; sl.w = i2;
    ((int4*)tokSlot)[t] = sl;
  }
}

// ---------------- prefix: 256-aligned bases; base[NE] = padded total
__global__ void prefix_k(const int* __restrict__ cnt, int* __restrict__ base) {
  if (threadIdx.x == 0) {
    int b = 0;
#pragma unroll
    for (int e = 0; e < NE; ++e) { base[e] = b; b += (cnt[e] + 255) & ~255; }
    base[NE] = b;
  }
}

// ---------------- stage 1: h = gate * silu(x@w1^T) * (x@w3^T)
// R13-exact inner loop (BM=256 x BN=64, BK=64, 4 waves, gld16 A bf16 + B raw
// fp32, cvt at fragment read). NEW: XCD-pinned 1-D grid — XCD r (bid&7) gets
// n-slots {nl*8+r}, walking ALL m-chunks per n-slot, so each (e,n) B panel
// slice is pulled from L3 once per XCD and re-read from that XCD's L2.
__global__ __launch_bounds__(256, 2) void ffn1_k(
    const uint16_t* __restrict__ xb, const float* __restrict__ w1,
    const float* __restrict__ w3, uint16_t* __restrict__ hbuf,
    const int* __restrict__ pairTok, const float* __restrict__ pairGate,
    const int* __restrict__ cnt, const int* __restrict__ base)
{
  // decode: bid in [0, 8*8*MG_BLKS). r = XCD, s = slot within XCD.
  const int bid = blockIdx.x;
  const int r   = bid & 7;
  const int s   = bid >> 3;            // [0, 8*MG_BLKS)
  const int nl  = s / MG_BLKS;         // [0,8)
  const int mi  = s - nl * MG_BLKS;    // [0,MG_BLKS)  m fastest within n-slot
  const int mg0 = mi * 256;
  if (mg0 >= base[NE]) return;
  const int n0  = (nl * 8 + r) * 64;   // [0, F_DIM/64)*64
  int e = 0;
#pragma unroll
  for (int k = 1; k < NE; ++k) if (mg0 >= base[k]) e = k;
  const int m0   = mg0 - base[e];
  const int cnte = cnt[e];
  const int tid  = threadIdx.x;
  const int lane = tid & 63;
  const int wid  = tid >> 6;
  const int wm   = (wid >> 1) * 128;   // 0 or 128
  const int wn   = (wid & 1) * 32;     // 0 or 32

  __shared__ __align__(16) uint16_t lsA [256 * 64];  // 32 KB bf16
  __shared__ __align__(16) float    lsB1[ 64 * 64];  // 16 KB fp32
  __shared__ __align__(16) float    lsB3[ 64 * 64];  // 16 KB fp32

  const float* w1e = w1 + (size_t)e * F_DIM * H_DIM;
  const float* w3e = w3 + (size_t)e * F_DIM * H_DIM;

  // A: 2048 16B-chunks (8 bf16), 8/thread; chunk c: row=c>>3, pos=c&7, kc=pos^(row&7)
  const uint16_t* asrc[8];
#pragma unroll
  for (int q = 0; q < 8; ++q) {
    const int c = q * 256 + tid;
    const int row = c >> 3, pos = c & 7;
    const int kc  = pos ^ (row & 7);
    int ar = m0 + row; if (ar >= cnte) ar = cnte - 1;
    const int tok = pairTok[e * T_TOK + ar];
    asrc[q] = xb + (size_t)tok * H_DIM + kc * 8;
  }
  // B (fp32): 64 rows x 16 chunks of 16B (4 f32); 1024 chunks each, 4/thread.
  const float* b1src[4];
  const float* b3src[4];
#pragma unroll
  for (int q = 0; q < 4; ++q) {
    const int c = q * 256 + tid;
    const int row = c >> 4, pos = c & 15;
    const int kc  = pos ^ (row & 15);
    b1src[q] = w1e + (size_t)(n0 + row) * H_DIM + kc * 4;
    b3src[q] = w3e + (size_t)(n0 + row) * H_DIM + kc * 4;
  }

  const f32x4 fz = {0.f, 0.f, 0.f, 0.f};
  f32x4 acc1[8][2], acc3[8][2];
#pragma unroll
  for (int i = 0; i < 8; ++i)
#pragma unroll
    for (int j = 0; j < 2; ++j) { acc1[i][j] = fz; acc3[i][j] = fz; }

  for (int kt = 0; kt < H_DIM; kt += 64) {
    __syncthreads();
#pragma unroll
    for (int q = 0; q < 8; ++q)
      gld16(asrc[q] + kt, &lsA[(q * 256 + tid) * 8]);
#pragma unroll
    for (int q = 0; q < 4; ++q) {
      gld16(b1src[q] + kt, &lsB1[(q * 256 + tid) * 4]);
      gld16(b3src[q] + kt, &lsB3[(q * 256 + tid) * 4]);
    }
    __syncthreads();
#pragma unroll
    for (int ks = 0; ks < 2; ++ks) {
      const int kg = ks * 4 + (lane >> 4);
      bf16x8 af[8], b1f[2], b3f[2];
#pragma unroll
      for (int i = 0; i < 8; ++i) {
        const int ar = wm + i * 16 + (lane & 15);
        af[i] = *(const bf16x8*)&lsA[ar * 64 + ((kg ^ (ar & 7)) * 8)];
      }
#pragma unroll
      for (int j = 0; j < 2; ++j) {
        const int br = wn + j * 16 + (lane & 15);
        b1f[j] = ldsB_frag(lsB1, br, kg);
        b3f[j] = ldsB_frag(lsB3, br, kg);
      }
#pragma unroll
      for (int i = 0; i < 8; ++i)
#pragma unroll
        for (int j = 0; j < 2; ++j) {
          acc1[i][j] = __builtin_amdgcn_mfma_f32_16x16x32_bf16(af[i], b1f[j], acc1[i][j], 0, 0, 0);
          acc3[i][j] = __builtin_amdgcn_mfma_f32_16x16x32_bf16(af[i], b3f[j], acc3[i][j], 0, 0, 0);
        }
    }
  }

  // epilogue: h = g * silu(a1) * a3 -> bf16. C/D: col=lane&15, row=(lane>>4)*4+r
  const int be = base[e];
#pragma unroll
  for (int i = 0; i < 8; ++i) {
#pragma unroll
    for (int rr = 0; rr < 4; ++rr) {
      const int lrow = m0 + wm + i * 16 + (lane >> 4) * 4 + rr;
      if (lrow < cnte) {
        const float g = pairGate[e * T_TOK + lrow];
        uint16_t* hp = hbuf + (size_t)(be + lrow) * F_DIM + n0 + wn + (lane & 15);
#pragma unroll
        for (int j = 0; j < 2; ++j) {
          const float a  = acc1[i][j][rr];
          const float hv = g * (a / (1.f + __expf(-a))) * acc3[i][j][rr];
          hp[j * 16] = f2bf(hv);
        }
      }
    }
  }
}

// ---------------- stage 2: y[row] = h[row] @ w2^T  (bf16 stores, no atomics)
// R13-exact inner loop (BM=256 x BN=128, 4 waves, acc[8][4], B raw fp32).
// XCD-pinned grid: XCD r owns n-block r (exactly 8 n-blocks), walks all m.
__global__ __launch_bounds__(256, 2) void ffn2_k(
    const uint16_t* __restrict__ hbuf, const float* __restrict__ w2,
    uint16_t* __restrict__ y, const int* __restrict__ cnt,
    const int* __restrict__ base)
{
  const int bid = blockIdx.x;
  const int r   = bid & 7;
  const int mi  = bid >> 3;            // [0, MG_BLKS)
  const int mg0 = mi * 256;
  if (mg0 >= base[NE]) return;
  const int n0  = r * 128;
  int e = 0;
#pragma unroll
  for (int k = 1; k < NE; ++k) if (mg0 >= base[k]) e = k;
  const int m0   = mg0 - base[e];
  const int cnte = cnt[e];
  const int tid  = threadIdx.x;
  const int lane = tid & 63;
  const int wid  = tid >> 6;
  const int wm   = (wid >> 1) * 128;   // 0 or 128
  const int wn   = (wid & 1) * 64;     // 0 or 64

  __shared__ __align__(16) uint16_t lsA[256 * 64];   // 32 KB bf16
  __shared__ __align__(16) float    lsB[128 * 64];   // 32 KB fp32

  const int be = base[e];
  const float* w2e = w2 + (size_t)e * H_DIM * F_DIM;

  const uint16_t* asrc[8];
#pragma unroll
  for (int q = 0; q < 8; ++q) {
    const int c = q * 256 + tid;
    const int row = c >> 3, pos = c & 7;
    const int kc  = pos ^ (row & 7);
    int rr = m0 + row; if (rr >= cnte) rr = cnte - 1;
    asrc[q] = hbuf + (size_t)(be + rr) * F_DIM + kc * 8;
  }
  // B (fp32): 128 rows x 16 chunks; 2048 chunks, 8/thread
  const float* bsrc[8];
#pragma unroll
  for (int q = 0; q < 8; ++q) {
    const int c = q * 256 + tid;
    const int row = c >> 4, pos = c & 15;
    const int kc  = pos ^ (row & 15);
    bsrc[q] = w2e + (size_t)(n0 + row) * F_DIM + kc * 4;
  }

  const f32x4 fz = {0.f, 0.f, 0.f, 0.f};
  f32x4 acc[8][4];
#pragma unroll
  for (int i = 0; i < 8; ++i)
#pragma unroll
    for (int j = 0; j < 4; ++j) acc[i][j] = fz;

  for (int kt = 0; kt < F_DIM; kt += 64) {
    __syncthreads();
#pragma unroll
    for (int q = 0; q < 8; ++q)
      gld16(asrc[q] + kt, &lsA[(q * 256 + tid) * 8]);
#pragma unroll
    for (int q = 0; q < 8; ++q)
      gld16(bsrc[q] + kt, &lsB[(q * 256 + tid) * 4]);
    __syncthreads();
#pragma unroll
    for (int ks = 0; ks < 2; ++ks) {
      const int kg = ks * 4 + (lane >> 4);
      bf16x8 af[8], bf[4];
#pragma unroll
      for (int i = 0; i < 8; ++i) {
        const int ar = wm + i * 16 + (lane & 15);
        af[i] = *(const bf16x8*)&lsA[ar * 64 + ((kg ^ (ar & 7)) * 8)];
      }
#pragma unroll
      for (int j = 0; j < 4; ++j) {
        const int br = wn + j * 16 + (lane & 15);
        bf[j] = ldsB_frag(lsB, br, kg);
      }
#pragma unroll
      for (int i = 0; i < 8; ++i)
#pragma unroll
        for (int j = 0; j < 4; ++j)
          acc[i][j] = __builtin_amdgcn_mfma_f32_16x16x32_bf16(af[i], bf[j], acc[i][j], 0, 0, 0);
    }
  }

  // epilogue: plain bf16 stores into pair-row buffer (gate already in h)
#pragma unroll
  for (int i = 0; i < 8; ++i) {
#pragma unroll
    for (int rr = 0; rr < 4; ++rr) {
      const int lrow = m0 + wm + i * 16 + (lane >> 4) * 4 + rr;
      if (lrow < cnte) {
        uint16_t* yp = y + (size_t)(be + lrow) * H_DIM + n0 + wn + (lane & 15);
#pragma unroll
        for (int j = 0; j < 4; ++j)
          yp[j * 16] = f2bf(acc[i][j][rr]);
      }
    }
  }
}

// ---------------- combine: out[t] = y[slot1(t)] + y[slot2(t)]  (fp32 out)
__global__ __launch_bounds__(256) void combine_k(
    const uint16_t* __restrict__ y, const int* __restrict__ tokSlot,
    const int* __restrict__ base, float* __restrict__ out)
{
  const int t = blockIdx.x * 2 + (threadIdx.x >> 7);
  const int c = (threadIdx.x & 127) * 8;
  const int4 s = ((const int4*)tokSlot)[t];
  const uint16_t* y1 = y + (size_t)(base[s.x] + s.y) * H_DIM + c;
  const uint16_t* y2 = y + (size_t)(base[s.z] + s.w) * H_DIM + c;
  const u16x8 a = *(const u16x8*)y1;
  const u16x8 b = *(const u16x8*)y2;
  float* op = out + (size_t)t * H_DIM + c;
  f32x4 o0, o1;
#pragma unroll
  for (int j = 0; j < 4; ++j) {
    o0[j] = __bfloat162float(__hip_bfloat16_raw{a[j]}) +
            __bfloat162float(__hip_bfloat16_raw{b[j]});
    o1[j] = __bfloat162float(__hip_bfloat16_raw{a[j + 4]}) +
            __bfloat162float(__hip_bfloat16_raw{b[j + 4]});
  }
  *(f32x4*)op       = o0;
  *(f32x4*)(op + 4) = o1;
}

extern "C" void kernel_launch(void* const* d_in, const int* in_sizes, int n_in,
                              void* d_out, int out_size, void* d_ws, size_t ws_size,
                              hipStream_t stream)
{
  const float* x  = (const float*)d_in[0];
  const float* wr = (const float*)d_in[1];
  const float* w1 = (const float*)d_in[2];
  const float* w2 = (const float*)d_in[3];
  const float* w3 = (const float*)d_in[4];
  float* out    = (float*)d_out;
  float* logits = out + (size_t)T_TOK * H_DIM;

  uint8_t* ws = (uint8_t*)d_ws;
  const size_t PADROWS  = (size_t)MG_BLKS * 256;                    // 10240
  const size_t XB_OFF   = 0;
  const size_t HB_OFF   = XB_OFF + (size_t)T_TOK * H_DIM * 2;       // 8 MB
  const size_t Y_OFF    = HB_OFF + PADROWS * F_DIM * 2;             // +80 MB
  const size_t PT_OFF   = Y_OFF + PADROWS * H_DIM * 2;              // +20 MB
  const size_t PG_OFF   = PT_OFF + (size_t)NE * T_TOK * 4;
  const size_t TS_OFF   = PG_OFF + (size_t)NE * T_TOK * 4;
  const size_t CNT_OFF  = TS_OFF + (size_t)T_TOK * 16;
  const size_t BASE_OFF = CNT_OFF + 64;
  const size_t NEED     = BASE_OFF + 64;
  if (ws_size < NEED) return;

  uint16_t* xb      = (uint16_t*)(ws + XB_OFF);
  uint16_t* hb      = (uint16_t*)(ws + HB_OFF);
  uint16_t* yb      = (uint16_t*)(ws + Y_OFF);
  int*      pairTok = (int*)(ws + PT_OFF);
  float*    pairGate= (float*)(ws + PG_OFF);
  int*      tokSlot = (int*)(ws + TS_OFF);
  int*      cnt     = (int*)(ws + CNT_OFF);
  int*      basep   = (int*)(ws + BASE_OFF);

  hipMemsetAsync(cnt, 0, 64, stream);
  router_k<<<T_TOK / 4, 256, 0, stream>>>(x, wr, logits, xb, pairTok, pairGate, tokSlot, cnt);
  prefix_k<<<1, 64, 0, stream>>>(cnt, basep);
  // XCD-pinned 1-D grids (see kernel headers)
  ffn1_k<<<8 * 8 * MG_BLKS, 256, 0, stream>>>(xb, w1, w3, hb, pairTok, pairGate, cnt, basep);
  ffn2_k<<<8 * MG_BLKS, 256, 0, stream>>>(hb, w2, yb, cnt, basep);
  combine_k<<<T_TOK / 2, 256, 0, stream>>>(yb, tokSlot, basep, out);
}